// Round 1
// baseline (1278.265 us; speedup 1.0000x reference)
//
#include <hip/hip_runtime.h>
#include <hip/hip_bf16.h>

#define EPSF 1e-8f

typedef __attribute__((ext_vector_type(8))) short short8;
typedef __attribute__((ext_vector_type(4))) float floatx4;

__device__ inline unsigned short f2bf(float v) {
    union { float f; unsigned int u; } un; un.f = v;
    unsigned int r = (un.u + 0x7fffu + ((un.u >> 16) & 1u)) >> 16;
    return (unsigned short)r;
}

// block = 256 threads (4 waves). Sum v over the block, broadcast to all threads.
__device__ inline float block_sum256(float v, float* lds4) {
    #pragma unroll
    for (int o = 32; o > 0; o >>= 1) v += __shfl_down(v, o, 64);
    int w = threadIdx.x >> 6, l = threadIdx.x & 63;
    if (l == 0) lds4[w] = v;
    __syncthreads();
    float tot = lds4[0] + lds4[1] + lds4[2] + lds4[3];
    __syncthreads();   // safe reuse of lds4
    return tot;
}

// --- K0: convert both weight matrices to bf16 (256x256 each) ---
__global__ __launch_bounds__(256) void k_conv_w(const float* __restrict__ Ws,
        const float* __restrict__ Wn, unsigned short* __restrict__ Wsb,
        unsigned short* __restrict__ Wnb) {
    int idx = blockIdx.x * 256 + threadIdx.x;
    Wsb[idx] = f2bf(Ws[idx]);
    Wnb[idx] = f2bf(Wn[idx]);
}

// --- K1: normalize_points(x) -> xn (bf16, Nx256) and xh (|h|, N) ---
__global__ __launch_bounds__(256) void k_norm_x(const float* __restrict__ x,
        unsigned short* __restrict__ xnb, float* __restrict__ xh, int N) {
    __shared__ float lds4[4];
    int i = blockIdx.x, t = threadIdx.x;
    float v = x[(size_t)i * 257 + t];
    float ss = block_sum256(v * v, lds4);
    float h = x[(size_t)i * 257 + 256];
    float sgn = (h < 0.f) ? -1.f : 1.f;       // sign(0) -> 1 per reference
    float f = (ss == 0.f) ? 1.f : v;          // zero_mask -> ones
    float nrm = (ss == 0.f) ? 16.f : sqrtf(ss);
    float scale = sgn / fmaxf(nrm, EPSF);
    xnb[(size_t)i * 256 + t] = f2bf(f * scale);
    if (t == 0) xh[i] = h * sgn;
}

// --- K2: out[m, 0:256] = row_normalize( xn[m,:] @ W^T ), row stride ldo ---
// Block: 16 rows x 256 cols; 4 waves, wave w owns cols [64w, 64w+64).
// MFMA 16x16x32 bf16. A rows unique per wave -> no LDS staging; W is L2-hot.
__global__ __launch_bounds__(256) void k_gemm_norm(
        const unsigned short* __restrict__ A,
        const unsigned short* __restrict__ W,
        float* __restrict__ out, int ldo, int N) {
    __shared__ float tile[16][260];           // +4 pad: store conflicts -> 2-way (free)
    __shared__ float rscale[16], rzero[16];
    int tid = threadIdx.x;
    int wave = tid >> 6, lane = tid & 63;
    int quad = lane >> 4, l16 = lane & 15;
    int row0 = blockIdx.x * 16;
    int arow = row0 + l16; if (arow >= N) arow = N - 1;
    const unsigned short* Ap = A + (size_t)arow * 256 + quad * 8;
    int jbase = wave * 64;
    const unsigned short* Wp0 = W + (size_t)(jbase + l16) * 256 + quad * 8;

    floatx4 acc0 = {0.f,0.f,0.f,0.f}, acc1 = acc0, acc2 = acc0, acc3 = acc0;
    #pragma unroll
    for (int ks = 0; ks < 256; ks += 32) {
        short8 a = *reinterpret_cast<const short8*>(Ap + ks);
        short8 b0 = *reinterpret_cast<const short8*>(Wp0 + ks);
        short8 b1 = *reinterpret_cast<const short8*>(Wp0 + 16 * 256 + ks);
        short8 b2 = *reinterpret_cast<const short8*>(Wp0 + 32 * 256 + ks);
        short8 b3 = *reinterpret_cast<const short8*>(Wp0 + 48 * 256 + ks);
        acc0 = __builtin_amdgcn_mfma_f32_16x16x32_bf16(a, b0, acc0, 0, 0, 0);
        acc1 = __builtin_amdgcn_mfma_f32_16x16x32_bf16(a, b1, acc1, 0, 0, 0);
        acc2 = __builtin_amdgcn_mfma_f32_16x16x32_bf16(a, b2, acc2, 0, 0, 0);
        acc3 = __builtin_amdgcn_mfma_f32_16x16x32_bf16(a, b3, acc3, 0, 0, 0);
    }
    // C/D layout: col = lane&15, row = quad*4 + reg  [verified m89]
    int colw = jbase + l16;
    #pragma unroll
    for (int reg = 0; reg < 4; ++reg) {
        tile[quad * 4 + reg][colw +  0] = acc0[reg];
        tile[quad * 4 + reg][colw + 16] = acc1[reg];
        tile[quad * 4 + reg][colw + 32] = acc2[reg];
        tile[quad * 4 + reg][colw + 48] = acc3[reg];
    }
    __syncthreads();
    // row sums of squares: 16 threads per row
    int r = tid >> 4, p = tid & 15;
    float ss = 0.f;
    #pragma unroll
    for (int i2 = 0; i2 < 16; ++i2) { float v = tile[r][p + 16 * i2]; ss += v * v; }
    #pragma unroll
    for (int o = 8; o > 0; o >>= 1) ss += __shfl_down(ss, o, 16);
    if (p == 0) {
        rzero[r] = (ss == 0.f) ? 1.f : 0.f;
        float nrm = (ss == 0.f) ? 16.f : sqrtf(ss);
        rscale[r] = 1.f / fmaxf(nrm, EPSF);
    }
    __syncthreads();
    #pragma unroll
    for (int rr = 0; rr < 16; ++rr) {
        if (row0 + rr < N) {
            float v = tile[rr][tid];
            if (rzero[rr] != 0.f) v = 1.f;
            out[(size_t)(row0 + rr) * ldo + tid] = v * rscale[rr];
        }
    }
}

// --- K3: edge scatter: agg[row] += y_full[col]; one wave per edge ---
__global__ __launch_bounds__(256) void k_scatter(
        const int* __restrict__ ei, const float* __restrict__ y,
        const float* __restrict__ xh,
        float* __restrict__ aggf, float* __restrict__ aggh,
        float* __restrict__ cnt, int E) {
    int e = blockIdx.x * 4 + (threadIdx.x >> 6);
    if (e >= E) return;
    int lane = threadIdx.x & 63;
    int r = ei[e];
    int c = ei[E + e];
    float4 v = reinterpret_cast<const float4*>(y + (size_t)c * 256)[lane];
    float* dst = aggf + (size_t)r * 256 + lane * 4;
    atomicAdd(dst + 0, v.x);
    atomicAdd(dst + 1, v.y);
    atomicAdd(dst + 2, v.z);
    atomicAdd(dst + 3, v.w);
    if (lane == 0) {
        atomicAdd(aggh + r, xh[c]);
        atomicAdd(cnt + r, 1.0f);
    }
}

// --- K4: mean+normalize aggregate, average with self (t==1.0f in fp32),
//         final normalize, write d_out (reads self_trans from d_out rows) ---
__global__ __launch_bounds__(256) void k_combine(
        const float* __restrict__ aggf, const float* __restrict__ aggh,
        const float* __restrict__ cnt, const float* __restrict__ xh,
        float* __restrict__ out, int N) {
    __shared__ float lds4[4];
    int i = blockIdx.x, t = threadIdx.x;
    float cn = fmaxf(cnt[i], 1.f);
    float mean = aggf[(size_t)i * 256 + t] / cn;
    float ss = block_sum256(mean * mean, lds4);
    float f = (ss == 0.f) ? 1.f : mean;       // no-in-edge node: zero_mask -> ones
    float nrm = (ss == 0.f) ? 16.f : sqrtf(ss);
    float of = f / fmaxf(nrm, EPSF);
    float oh = 1.f + aggh[i];
    float s = out[(size_t)i * 257 + t];       // self_trans f (written by k_gemm_norm)
    float a = 0.5f * (s + of);                // t = 0.5/(0.5+1e-8) == 1.0f in fp32
    float ss2 = block_sum256(a * a, lds4);
    float f2 = (ss2 == 0.f) ? 1.f : a;
    float nrm2 = (ss2 == 0.f) ? 16.f : sqrtf(ss2);
    float cf = f2 / fmaxf(nrm2, EPSF);
    out[(size_t)i * 257 + t] = cf;
    if (t == 0) out[(size_t)i * 257 + 256] = 0.5f * (xh[i] + oh);
}

extern "C" void kernel_launch(void* const* d_in, const int* in_sizes, int n_in,
                              void* d_out, int out_size, void* d_ws, size_t ws_size,
                              hipStream_t stream) {
    const float* x  = (const float*)d_in[0];
    const float* Ws = (const float*)d_in[1];
    const float* Wn = (const float*)d_in[2];
    const int*   ei = (const int*)d_in[3];
    int N = in_sizes[0] / 257;
    int E = in_sizes[3] / 2;
    float* out = (float*)d_out;

    char* ws = (char*)d_ws;
    size_t off = 0;
    auto alloc = [&](size_t bytes) {
        void* p = ws + off;
        off = (off + bytes + 255) & ~(size_t)255;
        return p;
    };
    unsigned short* xnb = (unsigned short*)alloc((size_t)N * 256 * 2);
    unsigned short* Wsb = (unsigned short*)alloc(256 * 256 * 2);
    unsigned short* Wnb = (unsigned short*)alloc(256 * 256 * 2);
    float* xh   = (float*)alloc((size_t)N * 4);
    float* y    = (float*)alloc((size_t)N * 256 * 4);
    float* aggf = (float*)alloc((size_t)N * 256 * 4);
    float* aggh = (float*)alloc((size_t)N * 4);
    float* cnt  = (float*)alloc((size_t)N * 4);

    // zero the aggregation region (aggf..cnt contiguous in ws)
    size_t zbytes = (size_t)(((char*)cnt + (size_t)N * 4) - (char*)aggf);
    hipMemsetAsync(aggf, 0, zbytes, stream);

    hipLaunchKernelGGL(k_conv_w, dim3(256), dim3(256), 0, stream, Ws, Wn, Wsb, Wnb);
    hipLaunchKernelGGL(k_norm_x, dim3(N), dim3(256), 0, stream, x, xnb, xh, N);
    int gb = (N + 15) / 16;
    hipLaunchKernelGGL(k_gemm_norm, dim3(gb), dim3(256), 0, stream, xnb, Wsb, out, 257, N);
    hipLaunchKernelGGL(k_gemm_norm, dim3(gb), dim3(256), 0, stream, xnb, Wnb, y, 256, N);
    hipLaunchKernelGGL(k_scatter, dim3((E + 3) / 4), dim3(256), 0, stream, ei, y, xh, aggf, aggh, cnt, E);
    hipLaunchKernelGGL(k_combine, dim3(N), dim3(256), 0, stream, aggf, aggh, cnt, xh, out, N);
}

// Round 2
// 267.519 us; speedup vs baseline: 4.7782x; 4.7782x over previous
//
#include <hip/hip_runtime.h>
#include <hip/hip_bf16.h>

#define EPSF 1e-8f

typedef __attribute__((ext_vector_type(8))) short short8;
typedef __attribute__((ext_vector_type(4))) float floatx4;

__device__ inline unsigned short f2bf(float v) {
    union { float f; unsigned int u; } un; un.f = v;
    unsigned int r = (un.u + 0x7fffu + ((un.u >> 16) & 1u)) >> 16;
    return (unsigned short)r;
}
__device__ inline float bf2f(unsigned short u) {
    union { unsigned int i; float f; } un; un.i = ((unsigned int)u) << 16;
    return un.f;
}

// block = 256 threads (4 waves). Sum v over the block, broadcast to all threads.
__device__ inline float block_sum256(float v, float* lds4) {
    #pragma unroll
    for (int o = 32; o > 0; o >>= 1) v += __shfl_down(v, o, 64);
    int w = threadIdx.x >> 6, l = threadIdx.x & 63;
    if (l == 0) lds4[w] = v;
    __syncthreads();
    float tot = lds4[0] + lds4[1] + lds4[2] + lds4[3];
    __syncthreads();   // safe reuse of lds4
    return tot;
}

// --- K0: convert both weight matrices to bf16 (256x256 each) ---
__global__ __launch_bounds__(256) void k_conv_w(const float* __restrict__ Ws,
        const float* __restrict__ Wn, unsigned short* __restrict__ Wsb,
        unsigned short* __restrict__ Wnb) {
    int idx = blockIdx.x * 256 + threadIdx.x;
    Wsb[idx] = f2bf(Ws[idx]);
    Wnb[idx] = f2bf(Wn[idx]);
}

// --- K1: normalize_points(x) -> xn (bf16, Nx256) and xh (|h|, N) ---
__global__ __launch_bounds__(256) void k_norm_x(const float* __restrict__ x,
        unsigned short* __restrict__ xnb, float* __restrict__ xh, int N) {
    __shared__ float lds4[4];
    int i = blockIdx.x, t = threadIdx.x;
    float v = x[(size_t)i * 257 + t];
    float ss = block_sum256(v * v, lds4);
    float h = x[(size_t)i * 257 + 256];
    float sgn = (h < 0.f) ? -1.f : 1.f;       // sign(0) -> 1 per reference
    float f = (ss == 0.f) ? 1.f : v;          // zero_mask -> ones
    float nrm = (ss == 0.f) ? 16.f : sqrtf(ss);
    float scale = sgn / fmaxf(nrm, EPSF);
    xnb[(size_t)i * 256 + t] = f2bf(f * scale);
    if (t == 0) xh[i] = h * sgn;
}

// --- K2: out = row_normalize( xn @ W^T ); fp32 (ldo stride) or bf16 output ---
// Block: 16 rows x 256 cols; wave w owns cols [64w, 64w+64). MFMA 16x16x32 bf16.
template <bool BF16OUT>
__global__ __launch_bounds__(256) void k_gemm_norm(
        const unsigned short* __restrict__ A,
        const unsigned short* __restrict__ W,
        float* __restrict__ out, unsigned short* __restrict__ outb,
        int ldo, int N) {
    __shared__ float tile[16][260];           // +4 pad: 2-way conflicts only (free)
    __shared__ float rscale[16], rzero[16];
    int tid = threadIdx.x;
    int wave = tid >> 6, lane = tid & 63;
    int quad = lane >> 4, l16 = lane & 15;
    int row0 = blockIdx.x * 16;
    int arow = row0 + l16; if (arow >= N) arow = N - 1;
    const unsigned short* Ap = A + (size_t)arow * 256 + quad * 8;
    int jbase = wave * 64;
    const unsigned short* Wp0 = W + (size_t)(jbase + l16) * 256 + quad * 8;

    floatx4 acc0 = {0.f,0.f,0.f,0.f}, acc1 = acc0, acc2 = acc0, acc3 = acc0;
    #pragma unroll
    for (int ks = 0; ks < 256; ks += 32) {
        short8 a = *reinterpret_cast<const short8*>(Ap + ks);
        short8 b0 = *reinterpret_cast<const short8*>(Wp0 + ks);
        short8 b1 = *reinterpret_cast<const short8*>(Wp0 + 16 * 256 + ks);
        short8 b2 = *reinterpret_cast<const short8*>(Wp0 + 32 * 256 + ks);
        short8 b3 = *reinterpret_cast<const short8*>(Wp0 + 48 * 256 + ks);
        acc0 = __builtin_amdgcn_mfma_f32_16x16x32_bf16(a, b0, acc0, 0, 0, 0);
        acc1 = __builtin_amdgcn_mfma_f32_16x16x32_bf16(a, b1, acc1, 0, 0, 0);
        acc2 = __builtin_amdgcn_mfma_f32_16x16x32_bf16(a, b2, acc2, 0, 0, 0);
        acc3 = __builtin_amdgcn_mfma_f32_16x16x32_bf16(a, b3, acc3, 0, 0, 0);
    }
    // C/D layout: col = lane&15, row = quad*4 + reg  [verified m89]
    int colw = jbase + l16;
    #pragma unroll
    for (int reg = 0; reg < 4; ++reg) {
        tile[quad * 4 + reg][colw +  0] = acc0[reg];
        tile[quad * 4 + reg][colw + 16] = acc1[reg];
        tile[quad * 4 + reg][colw + 32] = acc2[reg];
        tile[quad * 4 + reg][colw + 48] = acc3[reg];
    }
    __syncthreads();
    // row sums of squares: 16 threads per row
    int r = tid >> 4, p = tid & 15;
    float ss = 0.f;
    #pragma unroll
    for (int i2 = 0; i2 < 16; ++i2) { float v = tile[r][p + 16 * i2]; ss += v * v; }
    #pragma unroll
    for (int o = 8; o > 0; o >>= 1) ss += __shfl_down(ss, o, 16);
    if (p == 0) {
        rzero[r] = (ss == 0.f) ? 1.f : 0.f;
        float nrm = (ss == 0.f) ? 16.f : sqrtf(ss);
        rscale[r] = 1.f / fmaxf(nrm, EPSF);
    }
    __syncthreads();
    #pragma unroll
    for (int rr = 0; rr < 16; ++rr) {
        if (row0 + rr < N) {
            float v = tile[rr][tid];
            if (rzero[rr] != 0.f) v = 1.f;
            float o = v * rscale[rr];
            if (BF16OUT) outb[(size_t)(row0 + rr) * 256 + tid] = f2bf(o);
            else         out[(size_t)(row0 + rr) * ldo + tid] = o;
        }
    }
}

// --- S1: histogram of destination rows ---
__global__ __launch_bounds__(256) void k_hist(const int* __restrict__ ei,
        int* __restrict__ hist, int E) {
    for (int e = blockIdx.x * 256 + threadIdx.x; e < E; e += gridDim.x * 256)
        atomicAdd(&hist[ei[e]], 1);
}

// --- S2: exclusive prefix sum of hist -> offs and cursor (single block) ---
__global__ __launch_bounds__(1024) void k_scan(const int* __restrict__ hist,
        int* __restrict__ offs, int* __restrict__ cursor, int N) {
    __shared__ int partial[1024];
    int t = threadIdx.x;
    int C = (N + 1023) / 1024;
    int base = t * C;
    int s = 0;
    for (int i = 0; i < C; ++i) { int idx = base + i; if (idx < N) s += hist[idx]; }
    partial[t] = s;
    __syncthreads();
    // Hillis-Steele inclusive scan over 1024 partials
    for (int o = 1; o < 1024; o <<= 1) {
        int v = (t >= o) ? partial[t - o] : 0;
        __syncthreads();
        partial[t] += v;
        __syncthreads();
    }
    int run = (t == 0) ? 0 : partial[t - 1];   // exclusive
    for (int i = 0; i < C; ++i) {
        int idx = base + i;
        if (idx < N) { offs[idx] = run; cursor[idx] = run; run += hist[idx]; }
    }
}

// --- S3: bucket edges by destination row: scol = cols sorted by row ---
__global__ __launch_bounds__(256) void k_bucket(const int* __restrict__ ei,
        int* __restrict__ cursor, int* __restrict__ scol, int E) {
    int e = blockIdx.x * 256 + threadIdx.x;
    if (e >= E) return;
    int r = ei[e], c = ei[E + e];
    int pos = atomicAdd(&cursor[r], 1);
    scol[pos] = c;
}

// --- S4: per-node gather-aggregate (no atomics) + fused combine epilogue ---
// One 256-thread block per node; wave w gathers edge beg+w, beg+w+4, ...
__global__ __launch_bounds__(256) void k_agg_combine(
        const int* __restrict__ offs, const int* __restrict__ hist,
        const int* __restrict__ scol, const unsigned short* __restrict__ yb,
        const float* __restrict__ xh, float* __restrict__ out, int N) {
    __shared__ float red[4][256];
    __shared__ float hred[4];
    __shared__ float lds4[4];
    int i = blockIdx.x, t = threadIdx.x;
    int wave = t >> 6, lane = t & 63;
    int beg = offs[i], deg = hist[i];
    float a0 = 0.f, a1 = 0.f, a2 = 0.f, a3 = 0.f, ah = 0.f;
    for (int e = beg + wave; e < beg + deg; e += 4) {
        int c = scol[e];
        ushort4 v = reinterpret_cast<const ushort4*>(yb + (size_t)c * 256)[lane];
        a0 += bf2f(v.x); a1 += bf2f(v.y); a2 += bf2f(v.z); a3 += bf2f(v.w);
        if (lane == 0) ah += xh[c];
    }
    red[wave][lane * 4 + 0] = a0;
    red[wave][lane * 4 + 1] = a1;
    red[wave][lane * 4 + 2] = a2;
    red[wave][lane * 4 + 3] = a3;
    if (lane == 0) hred[wave] = ah;
    __syncthreads();
    float num  = red[0][t] + red[1][t] + red[2][t] + red[3][t];
    float aggh = hred[0] + hred[1] + hred[2] + hred[3];
    __syncthreads();                           // done reading red/hred
    float cn = (deg > 0) ? (float)deg : 1.f;
    float mean = num / cn;
    float ss = block_sum256(mean * mean, lds4);
    float f = (ss == 0.f) ? 1.f : mean;        // no-in-edge node: zero_mask -> ones
    float nrm = (ss == 0.f) ? 16.f : sqrtf(ss);
    float of = f / fmaxf(nrm, EPSF);
    float oh = 1.f + aggh;
    float s = out[(size_t)i * 257 + t];        // self_trans f (from k_gemm_norm)
    float av = 0.5f * (s + of);                // t = 0.5/(0.5+1e-8) == 1.0f in fp32
    float ss2 = block_sum256(av * av, lds4);
    float f2 = (ss2 == 0.f) ? 1.f : av;
    float n2 = (ss2 == 0.f) ? 16.f : sqrtf(ss2);
    out[(size_t)i * 257 + t] = f2 / fmaxf(n2, EPSF);
    if (t == 0) out[(size_t)i * 257 + 256] = 0.5f * (xh[i] + oh);
}

extern "C" void kernel_launch(void* const* d_in, const int* in_sizes, int n_in,
                              void* d_out, int out_size, void* d_ws, size_t ws_size,
                              hipStream_t stream) {
    const float* x  = (const float*)d_in[0];
    const float* Ws = (const float*)d_in[1];
    const float* Wn = (const float*)d_in[2];
    const int*   ei = (const int*)d_in[3];
    int N = in_sizes[0] / 257;
    int E = in_sizes[3] / 2;
    float* out = (float*)d_out;

    char* ws = (char*)d_ws;
    size_t off = 0;
    auto alloc = [&](size_t bytes) {
        void* p = ws + off;
        off = (off + bytes + 255) & ~(size_t)255;
        return p;
    };
    unsigned short* xnb = (unsigned short*)alloc((size_t)N * 256 * 2);
    unsigned short* Wsb = (unsigned short*)alloc(256 * 256 * 2);
    unsigned short* Wnb = (unsigned short*)alloc(256 * 256 * 2);
    float* xh   = (float*)alloc((size_t)N * 4);
    unsigned short* yb = (unsigned short*)alloc((size_t)N * 256 * 2);
    int* hist   = (int*)alloc((size_t)N * 4);
    int* offs   = (int*)alloc((size_t)N * 4);
    int* cursor = (int*)alloc((size_t)N * 4);
    int* scol   = (int*)alloc((size_t)E * 4);

    hipMemsetAsync(hist, 0, (size_t)N * 4, stream);

    // CSR build (independent of the transforms)
    hipLaunchKernelGGL(k_hist, dim3(128), dim3(256), 0, stream, ei, hist, E);
    hipLaunchKernelGGL(k_scan, dim3(1), dim3(1024), 0, stream, hist, offs, cursor, N);
    hipLaunchKernelGGL(k_bucket, dim3((E + 255) / 256), dim3(256), 0, stream, ei, cursor, scol, E);

    // transforms
    hipLaunchKernelGGL(k_conv_w, dim3(256), dim3(256), 0, stream, Ws, Wn, Wsb, Wnb);
    hipLaunchKernelGGL(k_norm_x, dim3(N), dim3(256), 0, stream, x, xnb, xh, N);
    int gb = (N + 15) / 16;
    hipLaunchKernelGGL((k_gemm_norm<false>), dim3(gb), dim3(256), 0, stream,
                       xnb, Wsb, out, (unsigned short*)nullptr, 257, N);
    hipLaunchKernelGGL((k_gemm_norm<true>), dim3(gb), dim3(256), 0, stream,
                       xnb, Wnb, (float*)nullptr, yb, 256, N);

    // gather-aggregate + combine (no data atomics)
    hipLaunchKernelGGL(k_agg_combine, dim3(N), dim3(256), 0, stream,
                       offs, hist, scol, yb, xh, out, N);
}

// Round 3
// 234.849 us; speedup vs baseline: 5.4429x; 1.1391x over previous
//
#include <hip/hip_runtime.h>
#include <hip/hip_bf16.h>

#define EPSF 1e-8f

typedef __attribute__((ext_vector_type(8))) short short8;
typedef __attribute__((ext_vector_type(4))) float floatx4;

__device__ inline unsigned short f2bf(float v) {
    union { float f; unsigned int u; } un; un.f = v;
    unsigned int r = (un.u + 0x7fffu + ((un.u >> 16) & 1u)) >> 16;
    return (unsigned short)r;
}
__device__ inline float bf2f(unsigned short u) {
    union { unsigned int i; float f; } un; un.i = ((unsigned int)u) << 16;
    return un.f;
}

// block = 256 threads (4 waves). Sum v over the block, broadcast to all threads.
__device__ inline float block_sum256(float v, float* lds4) {
    #pragma unroll
    for (int o = 32; o > 0; o >>= 1) v += __shfl_down(v, o, 64);
    int w = threadIdx.x >> 6, l = threadIdx.x & 63;
    if (l == 0) lds4[w] = v;
    __syncthreads();
    float tot = lds4[0] + lds4[1] + lds4[2] + lds4[3];
    __syncthreads();
    return tot;
}

// --- K0: convert both weight matrices to bf16 (256x256 each) ---
__global__ __launch_bounds__(256) void k_conv_w(const float* __restrict__ Ws,
        const float* __restrict__ Wn, unsigned short* __restrict__ Wsb,
        unsigned short* __restrict__ Wnb) {
    int idx = blockIdx.x * 256 + threadIdx.x;
    Wsb[idx] = f2bf(Ws[idx]);
    Wnb[idx] = f2bf(Wn[idx]);
}

// --- K1: prep: xnb = bf16( sgn(h) * f ), xh = |h|.  (input normalize cancels
//     under the post-GEMM row-normalize; sgn folds into the cast) ---
__global__ __launch_bounds__(256) void k_prep(const float* __restrict__ x,
        unsigned short* __restrict__ xnb, float* __restrict__ xh, int N) {
    int i = blockIdx.x, t = threadIdx.x;
    float h = x[(size_t)i * 257 + 256];
    float sgn = (h < 0.f) ? -1.f : 1.f;       // sign(0) -> 1 per reference
    float v = x[(size_t)i * 257 + t] * sgn;
    xnb[(size_t)i * 256 + t] = f2bf(v);
    if (t == 0) xh[i] = h * sgn;
}

// --- K2: fused double GEMM + row-normalize.
// 32 rows/block, 256 threads (4 waves); wave w owns cols [64w,64w+64).
// Computes normalize(A @ Ws^T) -> out (fp32, stride 257) and
//          normalize(A @ Wn^T) -> yb  (bf16, stride 256) in one pass over A.
__global__ __launch_bounds__(256) void k_gemm2(
        const unsigned short* __restrict__ A,
        const unsigned short* __restrict__ Wsb,
        const unsigned short* __restrict__ Wnb,
        float* __restrict__ out, unsigned short* __restrict__ yb, int N) {
    __shared__ unsigned short As[32][264];     // +8 pad: rows offset 4 banks -> 2-way max
    __shared__ float pss[4][2][2][16];         // [wave][mat][mtile][row] partial ss
    int tid = threadIdx.x;
    int wave = tid >> 6, lane = tid & 63;
    int quad = lane >> 4, l16 = lane & 15;
    int row0 = blockIdx.x * 32;

    // stage A-tile (bf16): 4 passes x (8 rows x 256 cols)
    #pragma unroll
    for (int pass = 0; pass < 4; ++pass) {
        int rr = pass * 8 + (tid >> 5);
        int cc = (tid & 31) * 8;
        int gr = row0 + rr; if (gr >= N) gr = N - 1;
        short8 v = *reinterpret_cast<const short8*>(A + (size_t)gr * 256 + cc);
        *reinterpret_cast<short8*>(&As[rr][cc]) = v;
    }
    __syncthreads();

    int jcol = wave * 64 + l16;                // W row = output col (group g adds 16g)
    const unsigned short* WpS = Wsb + (size_t)jcol * 256 + quad * 8;
    const unsigned short* WpN = Wnb + (size_t)jcol * 256 + quad * 8;

    floatx4 acc[2][2][4];                      // [mat][mtile][group]
    #pragma unroll
    for (int m = 0; m < 2; ++m)
        #pragma unroll
        for (int q = 0; q < 2; ++q)
            #pragma unroll
            for (int g = 0; g < 4; ++g) acc[m][q][g] = floatx4{0.f,0.f,0.f,0.f};

    #pragma unroll 2
    for (int ks = 0; ks < 256; ks += 32) {
        short8 a0 = *reinterpret_cast<const short8*>(&As[l16][quad * 8 + ks]);
        short8 a1 = *reinterpret_cast<const short8*>(&As[16 + l16][quad * 8 + ks]);
        #pragma unroll
        for (int g = 0; g < 4; ++g) {
            short8 ws = *reinterpret_cast<const short8*>(WpS + (size_t)g * 16 * 256 + ks);
            short8 wn = *reinterpret_cast<const short8*>(WpN + (size_t)g * 16 * 256 + ks);
            acc[0][0][g] = __builtin_amdgcn_mfma_f32_16x16x32_bf16(a0, ws, acc[0][0][g], 0, 0, 0);
            acc[0][1][g] = __builtin_amdgcn_mfma_f32_16x16x32_bf16(a1, ws, acc[0][1][g], 0, 0, 0);
            acc[1][0][g] = __builtin_amdgcn_mfma_f32_16x16x32_bf16(a0, wn, acc[1][0][g], 0, 0, 0);
            acc[1][1][g] = __builtin_amdgcn_mfma_f32_16x16x32_bf16(a1, wn, acc[1][1][g], 0, 0, 0);
        }
    }

    // row sum-of-squares partials: reduce over l16 within each quad (rows quad*4+reg)
    #pragma unroll
    for (int m = 0; m < 2; ++m)
        #pragma unroll
        for (int q = 0; q < 2; ++q) {
            float s[4];
            #pragma unroll
            for (int reg = 0; reg < 4; ++reg) {
                float v = 0.f;
                #pragma unroll
                for (int g = 0; g < 4; ++g) v += acc[m][q][g][reg] * acc[m][q][g][reg];
                #pragma unroll
                for (int o = 8; o > 0; o >>= 1) v += __shfl_down(v, o, 64);
                s[reg] = v;                    // valid at l16 == 0
            }
            if (l16 == 0) {
                #pragma unroll
                for (int reg = 0; reg < 4; ++reg)
                    pss[wave][m][q][quad * 4 + reg] = s[reg];
            }
        }
    __syncthreads();

    // scale + store (C/D: col = l16 (+16g), row = quad*4+reg  [verified m89])
    #pragma unroll
    for (int m = 0; m < 2; ++m)
        #pragma unroll
        for (int q = 0; q < 2; ++q)
            #pragma unroll
            for (int reg = 0; reg < 4; ++reg) {
                int r16 = quad * 4 + reg;
                int gr = row0 + q * 16 + r16;
                if (gr >= N) continue;
                float ss = pss[0][m][q][r16] + pss[1][m][q][r16]
                         + pss[2][m][q][r16] + pss[3][m][q][r16];
                bool zero = (ss == 0.f);
                float scale = zero ? 0.f : (1.f / fmaxf(sqrtf(ss), EPSF));
                #pragma unroll
                for (int g = 0; g < 4; ++g) {
                    int col = wave * 64 + 16 * g + l16;
                    float val = zero ? 0.0625f : acc[m][q][g][reg] * scale;
                    if (m == 0) out[(size_t)gr * 257 + col] = val;
                    else        yb[(size_t)gr * 256 + col] = f2bf(val);
                }
            }
}

// --- S1: histogram of destination rows ---
__global__ __launch_bounds__(256) void k_hist(const int* __restrict__ ei,
        int* __restrict__ hist, int E) {
    for (int e = blockIdx.x * 256 + threadIdx.x; e < E; e += gridDim.x * 256)
        atomicAdd(&hist[ei[e]], 1);
}

// --- S2: exclusive prefix sum (single block, wave-shfl scan, 1 barrier) ---
__global__ __launch_bounds__(1024) void k_scan(const int* __restrict__ hist,
        int* __restrict__ offs, int* __restrict__ cursor, int N) {
    __shared__ int wtot[16];
    int t = threadIdx.x, lane = t & 63, wv = t >> 6;
    int C = (N + 1023) >> 10;                  // per-thread chunk (<=32)
    int base = t * C;
    int vals[32];
    int s = 0;
    #pragma unroll
    for (int i = 0; i < 32; ++i) {
        if (i < C) {
            int idx = base + i;
            vals[i] = (idx < N) ? hist[idx] : 0;
            s += vals[i];
        }
    }
    int incl = s;
    #pragma unroll
    for (int o = 1; o < 64; o <<= 1) {
        int v = __shfl_up(incl, o, 64);
        if (lane >= o) incl += v;
    }
    if (lane == 63) wtot[wv] = incl;
    __syncthreads();
    int wbase = 0;
    for (int w = 0; w < wv; ++w) wbase += wtot[w];
    int run = wbase + incl - s;                // exclusive base for this thread
    #pragma unroll
    for (int i = 0; i < 32; ++i) {
        if (i < C) {
            int idx = base + i;
            if (idx < N) { offs[idx] = run; cursor[idx] = run; run += vals[i]; }
        }
    }
}

// --- S3: bucket edges by destination row: scol = cols sorted by row ---
__global__ __launch_bounds__(256) void k_bucket(const int* __restrict__ ei,
        int* __restrict__ cursor, int* __restrict__ scol, int E) {
    int e = blockIdx.x * 256 + threadIdx.x;
    if (e >= E) return;
    int r = ei[e], c = ei[E + e];
    int pos = atomicAdd(&cursor[r], 1);
    scol[pos] = c;
}

// --- S4: per-node gather-aggregate (no atomics) + fused combine epilogue ---
__global__ __launch_bounds__(256) void k_agg_combine(
        const int* __restrict__ offs, const int* __restrict__ hist,
        const int* __restrict__ scol, const unsigned short* __restrict__ yb,
        const float* __restrict__ xh, float* __restrict__ out, int N) {
    __shared__ float red[4][256];
    __shared__ float hred[4];
    __shared__ float lds4[4];
    int i = blockIdx.x, t = threadIdx.x;
    int wave = t >> 6, lane = t & 63;
    int beg = offs[i], deg = hist[i];
    float a0 = 0.f, a1 = 0.f, a2 = 0.f, a3 = 0.f, ah = 0.f;
    for (int e = beg + wave; e < beg + deg; e += 4) {
        int c = scol[e];
        ushort4 v = reinterpret_cast<const ushort4*>(yb + (size_t)c * 256)[lane];
        a0 += bf2f(v.x); a1 += bf2f(v.y); a2 += bf2f(v.z); a3 += bf2f(v.w);
        if (lane == 0) ah += xh[c];
    }
    red[wave][lane * 4 + 0] = a0;
    red[wave][lane * 4 + 1] = a1;
    red[wave][lane * 4 + 2] = a2;
    red[wave][lane * 4 + 3] = a3;
    if (lane == 0) hred[wave] = ah;
    __syncthreads();
    float num  = red[0][t] + red[1][t] + red[2][t] + red[3][t];
    float aggh = hred[0] + hred[1] + hred[2] + hred[3];
    __syncthreads();
    float cn = (deg > 0) ? (float)deg : 1.f;
    float mean = num / cn;
    float ss = block_sum256(mean * mean, lds4);
    float f = (ss == 0.f) ? 1.f : mean;        // no-in-edge node: zero_mask -> ones
    float nrm = (ss == 0.f) ? 16.f : sqrtf(ss);
    float of = f / fmaxf(nrm, EPSF);
    float oh = 1.f + aggh;
    float s = out[(size_t)i * 257 + t];        // self_trans f (from k_gemm2)
    float av = 0.5f * (s + of);                // t = 0.5/(0.5+1e-8) == 1.0f in fp32
    float ss2 = block_sum256(av * av, lds4);
    float f2 = (ss2 == 0.f) ? 1.f : av;
    float n2 = (ss2 == 0.f) ? 16.f : sqrtf(ss2);
    out[(size_t)i * 257 + t] = f2 / fmaxf(n2, EPSF);
    if (t == 0) out[(size_t)i * 257 + 256] = 0.5f * (xh[i] + oh);
}

extern "C" void kernel_launch(void* const* d_in, const int* in_sizes, int n_in,
                              void* d_out, int out_size, void* d_ws, size_t ws_size,
                              hipStream_t stream) {
    const float* x  = (const float*)d_in[0];
    const float* Ws = (const float*)d_in[1];
    const float* Wn = (const float*)d_in[2];
    const int*   ei = (const int*)d_in[3];
    int N = in_sizes[0] / 257;
    int E = in_sizes[3] / 2;
    float* out = (float*)d_out;

    char* ws = (char*)d_ws;
    size_t off = 0;
    auto alloc = [&](size_t bytes) {
        void* p = ws + off;
        off = (off + bytes + 255) & ~(size_t)255;
        return p;
    };
    unsigned short* xnb = (unsigned short*)alloc((size_t)N * 256 * 2);
    unsigned short* Wsb = (unsigned short*)alloc(256 * 256 * 2);
    unsigned short* Wnb = (unsigned short*)alloc(256 * 256 * 2);
    float* xh   = (float*)alloc((size_t)N * 4);
    unsigned short* yb = (unsigned short*)alloc((size_t)N * 256 * 2);
    int* hist   = (int*)alloc((size_t)N * 4);
    int* offs   = (int*)alloc((size_t)N * 4);
    int* cursor = (int*)alloc((size_t)N * 4);
    int* scol   = (int*)alloc((size_t)E * 4);

    hipMemsetAsync(hist, 0, (size_t)N * 4, stream);

    // CSR build
    hipLaunchKernelGGL(k_hist, dim3(128), dim3(256), 0, stream, ei, hist, E);
    hipLaunchKernelGGL(k_scan, dim3(1), dim3(1024), 0, stream, hist, offs, cursor, N);
    hipLaunchKernelGGL(k_bucket, dim3((E + 255) / 256), dim3(256), 0, stream, ei, cursor, scol, E);

    // transforms
    hipLaunchKernelGGL(k_conv_w, dim3(256), dim3(256), 0, stream, Ws, Wn, Wsb, Wnb);
    hipLaunchKernelGGL(k_prep, dim3(N), dim3(256), 0, stream, x, xnb, xh, N);
    hipLaunchKernelGGL(k_gemm2, dim3((N + 31) / 32), dim3(256), 0, stream,
                       xnb, Wsb, Wnb, out, yb, N);

    // gather-aggregate + combine
    hipLaunchKernelGGL(k_agg_combine, dim3(N), dim3(256), 0, stream,
                       offs, hist, scol, yb, xh, out, N);
}